// Round 1
// baseline (150.406 us; speedup 1.0000x reference)
//
#include <hip/hip_runtime.h>

// Problem constants
#define N_   8
#define C_   32
#define H_   256
#define W_   256
#define HW_  (H_ * W_)

// ---------------------------------------------------------------------------
// Kernel 1: per-(n,c) instance-norm stats, folded with gamma/beta into
//           scale/shift:  xn = x*scale + shift
// grid = 256 (one wg per (n,c) plane), block = 256
// ---------------------------------------------------------------------------
__global__ __launch_bounds__(256) void stats_kernel(
    const float* __restrict__ x, const float* __restrict__ gamma,
    const float* __restrict__ beta, float2* __restrict__ ss)
{
    const int nc = blockIdx.x;      // n*32 + c
    const int t  = threadIdx.x;
    const float4* p = (const float4*)(x + (size_t)nc * HW_);

    double s = 0.0, q = 0.0;
    #pragma unroll 4
    for (int i = t; i < HW_ / 4; i += 256) {
        float4 v = p[i];
        double a = v.x, b = v.y, c = v.z, d = v.w;
        s += a + b + c + d;
        q += a * a + b * b + c * c + d * d;
    }
    // wave (64-lane) butterfly, then cross-wave via LDS
    #pragma unroll
    for (int off = 32; off > 0; off >>= 1) {
        s += __shfl_down(s, off);
        q += __shfl_down(q, off);
    }
    __shared__ double rs[4], rq[4];
    const int wid = t >> 6;
    if ((t & 63) == 0) { rs[wid] = s; rq[wid] = q; }
    __syncthreads();
    if (t == 0) {
        double S = rs[0] + rs[1] + rs[2] + rs[3];
        double Q = rq[0] + rq[1] + rq[2] + rq[3];
        double mean = S / (double)HW_;
        double var  = Q / (double)HW_ - mean * mean;
        double rstd = 1.0 / sqrt(var + 1e-5);
        int c = nc & (C_ - 1);
        float scale = (float)((double)gamma[c] * rstd);
        float shift = (float)((double)beta[c] - mean * (double)scale);
        ss[nc] = make_float2(scale, shift);
    }
}

// ---------------------------------------------------------------------------
// Kernel 2: fused  normalize -> (collapsed sparse field) -> 1x1 conv -> relu
//
// Math (derived from the reference):
//   For each 2x2 spatial pooling block over the padded grid (h-blocks align
//   to even h since ht=2; w-blocks cover {2j-1, 2j} since wl=1), with
//   m = max of the 4 normalized values (spatial pads = 0) and s* = first
//   argmax position (row-major r,kw order):
//     m > 0  -> collapsed += 0.75*m at s*   (depths 1,2,4 survive the crop)
//     m <= 0 -> collapsed += 0.25*m at s*   (middle depth block only),
//               and only if s* is a real (non-pad) position.
//   Then out[n,o,h,w] = relu(b[o] + sum_c W[o,c] * collapsed[n,c,h,w]).
//
// grid = (128 h-pairs, 8 n), block = 256
// ---------------------------------------------------------------------------
__global__ __launch_bounds__(256) void fused_kernel(
    const float* __restrict__ x, const float2* __restrict__ ss,
    const float* __restrict__ Wm, const float* __restrict__ bias,
    float* __restrict__ out)
{
    const int k = blockIdx.x;   // h-pair index: rows 2k, 2k+1
    const int n = blockIdx.y;
    const int t = threadIdx.x;

    __shared__ float         sVal[C_][132];   // per (c, j-block) contribution value
    __shared__ unsigned char sPos[C_][132];   // per (c, j-block) argmax position 0..3
    __shared__ float         sWT[C_][C_];     // sWT[c][o] = W[o,c]

    // stage W^T
    for (int i = t; i < C_ * C_; i += 256) {
        int o = i >> 5, c = i & 31;
        sWT[c][o] = Wm[i];
    }

    // ---- Phase A: per (c, j) pooling-block reduction -----------------------
    // j in [0,129): block covers w in {2j-1, 2j};  j=0 left pad, j=128 right pad
    const float* xrow = x + ((size_t)n * C_) * HW_ + (size_t)(2 * k) * W_;
    for (int task = t; task < C_ * 129; task += 256) {
        int c = task / 129;
        int j = task - c * 129;
        float2 sc = ss[n * C_ + c];
        const float* r0 = xrow + (size_t)c * HW_;
        const float* r1 = r0 + W_;
        int wl = 2 * j - 1, wr = 2 * j;
        float v0 = (j > 0)   ? fmaf(r0[wl], sc.x, sc.y) : 0.f;
        float v1 = (j < 128) ? fmaf(r0[wr], sc.x, sc.y) : 0.f;
        float v2 = (j > 0)   ? fmaf(r1[wl], sc.x, sc.y) : 0.f;
        float v3 = (j < 128) ? fmaf(r1[wr], sc.x, sc.y) : 0.f;
        float m = v0; int p = 0;
        if (v1 > m) { m = v1; p = 1; }
        if (v2 > m) { m = v2; p = 2; }
        if (v3 > m) { m = v3; p = 3; }
        float val = m * (m > 0.f ? 0.75f : 0.25f);
        // position is a spatial pad? (kw=0 <-> p even <-> w=2j-1; kw=1 <-> w=2j)
        bool padpos = (((p & 1) == 0) && j == 0) || (((p & 1) == 1) && j == 128);
        if (padpos) val = 0.f;
        sVal[c][j] = val;
        sPos[c][j] = (unsigned char)p;
    }
    __syncthreads();

    // ---- Phase B: gather + 32x32 channel mix -------------------------------
    // wave-uniform o-octet: t = o4*64 + wt ; lane owns w = 4*wt + dw, dw=0..3
    const int o4 = t >> 6;          // 0..3  -> o in [8*o4, 8*o4+8)
    const int wt = t & 63;          // 0..63
    const int ob = o4 * 8;

    float b8[8];
    #pragma unroll
    for (int oo = 0; oo < 8; ++oo) b8[oo] = bias[ob + oo];

    float acc[2][4][8];
    #pragma unroll
    for (int r = 0; r < 2; ++r)
        #pragma unroll
        for (int dw = 0; dw < 4; ++dw)
            #pragma unroll
            for (int oo = 0; oo < 8; ++oo) acc[r][dw][oo] = b8[oo];

    // blocks touched by this lane's 4 columns: jA=2wt (kw=1 at dw0),
    // jB=2wt+1 (kw=0 at dw1, kw=1 at dw2), jC=2wt+2 (kw=0 at dw3)
    for (int c = 0; c < C_; ++c) {
        float w8[8];
        #pragma unroll
        for (int oo = 0; oo < 8; ++oo) w8[oo] = sWT[c][ob + oo];
        float vA = sVal[c][2 * wt];
        float vB = sVal[c][2 * wt + 1];
        float vC = sVal[c][2 * wt + 2];
        int   pA = sPos[c][2 * wt];
        int   pB = sPos[c][2 * wt + 1];
        int   pC = sPos[c][2 * wt + 2];
        // masked values for (row r, dw): pos code = r*2 + kw
        float m00 = (pA == 1) ? vA : 0.f, m10 = (pA == 3) ? vA : 0.f;
        float m01 = (pB == 0) ? vB : 0.f, m11 = (pB == 2) ? vB : 0.f;
        float m02 = (pB == 1) ? vB : 0.f, m12 = (pB == 3) ? vB : 0.f;
        float m03 = (pC == 0) ? vC : 0.f, m13 = (pC == 2) ? vC : 0.f;
        #pragma unroll
        for (int oo = 0; oo < 8; ++oo) {
            float w = w8[oo];
            acc[0][0][oo] = fmaf(m00, w, acc[0][0][oo]);
            acc[0][1][oo] = fmaf(m01, w, acc[0][1][oo]);
            acc[0][2][oo] = fmaf(m02, w, acc[0][2][oo]);
            acc[0][3][oo] = fmaf(m03, w, acc[0][3][oo]);
            acc[1][0][oo] = fmaf(m10, w, acc[1][0][oo]);
            acc[1][1][oo] = fmaf(m11, w, acc[1][1][oo]);
            acc[1][2][oo] = fmaf(m12, w, acc[1][2][oo]);
            acc[1][3][oo] = fmaf(m13, w, acc[1][3][oo]);
        }
    }

    // ---- store: relu + float4, coalesced across wt -------------------------
    #pragma unroll
    for (int r = 0; r < 2; ++r)
        #pragma unroll
        for (int oo = 0; oo < 8; ++oo) {
            float4 v;
            v.x = fmaxf(acc[r][0][oo], 0.f);
            v.y = fmaxf(acc[r][1][oo], 0.f);
            v.z = fmaxf(acc[r][2][oo], 0.f);
            v.w = fmaxf(acc[r][3][oo], 0.f);
            float* dst = out + ((size_t)(n * C_ + ob + oo) * HW_
                               + (size_t)(2 * k + r) * W_ + 4 * wt);
            *(float4*)dst = v;
        }
}

extern "C" void kernel_launch(void* const* d_in, const int* in_sizes, int n_in,
                              void* d_out, int out_size, void* d_ws, size_t ws_size,
                              hipStream_t stream) {
    const float* x     = (const float*)d_in[0];
    const float* gamma = (const float*)d_in[1];
    const float* beta  = (const float*)d_in[2];
    const float* Wm    = (const float*)d_in[3];
    const float* bias  = (const float*)d_in[4];
    float* out  = (float*)d_out;
    float2* ss  = (float2*)d_ws;    // 256 x {scale, shift}

    stats_kernel<<<N_ * C_, 256, 0, stream>>>(x, gamma, beta, ss);
    fused_kernel<<<dim3(H_ / 2, N_), 256, 0, stream>>>(x, ss, Wm, bias, out);
}